// Round 5
// baseline (284.356 us; speedup 1.0000x reference)
//
#include <hip/hip_runtime.h>
#include <math.h>

#define B_ 512
#define T_ 256
#define I_ 7
#define H_ 64
#define L_ 16
#define NCH_ (T_ / L_)
#define L2E 1.44269504089f
#define GUARD2 (-21.64f)

typedef short bf16x8 __attribute__((ext_vector_type(8)));
typedef short short4v __attribute__((ext_vector_type(4)));
typedef float f32x4 __attribute__((ext_vector_type(4)));

__device__ __forceinline__ unsigned short f2bf(float f) {
  unsigned u = __float_as_uint(f);
  u += 0x7fff + ((u >> 16) & 1);          // RNE
  return (unsigned short)(u >> 16);
}
__device__ __forceinline__ float ex2(float x) { return __builtin_amdgcn_exp2f(x); }
__device__ __forceinline__ float lg2(float x) { return __builtin_amdgcn_logf(x); }
// log2(sigmoid(a)) given a already scaled by log2e
__device__ __forceinline__ float logsig2(float a2) {
  return (a2 < GUARD2) ? a2 : -lg2(1.f + ex2(-a2));
}
__device__ __forceinline__ float sig2(float a2) {
  return __fdividef(1.f, 1.f + ex2(-a2));
}

// ---- consumer: v projection for own 16 rows, 4 (r,t) pairs per lane ----
#define CONS_V(BUF, XP) do {                                                  \
  unsigned short vv[4];                                                       \
  _Pragma("unroll") for (int i2 = 0; i2 < 4; ++i2) {                          \
    const int t = 4 * quad + i2;                                              \
    float vp = bV;                                                            \
    _Pragma("unroll") for (int jj = 0; jj < 7; ++jj)                          \
      vp = fmaf((XP)[t * 7 + jj], wVl[jj], vp);                               \
    vv[i2] = f2bf(vp);                                                        \
  }                                                                           \
  short4v pk = {(short)vv[0], (short)vv[1], (short)vv[2], (short)vv[3]};      \
  *(short4v*)&sVT[BUF][16 * w + sl][4 * quad] = pk;                           \
} while (0)

// ---- w2: i,k,f for all 64 channels (lane = channel). ls/ik stored for the
// block's own 32 channels; k~ (and its transpose) for all 64. ----
#define PROD_IKF(BUF, XP) do {                                                \
  float cl[16], ikv[16];                                                      \
  _Pragma("unroll") for (int t = 0; t < 16; ++t) {                            \
    float xs[7];                                                              \
    _Pragma("unroll") for (int jj = 0; jj < 7; ++jj) xs[jj] = (XP)[t * 7 + jj]; \
    float fp = bF2, ip = bI2, kp = bK;                                        \
    _Pragma("unroll") for (int jj = 0; jj < 7; ++jj) {                        \
      fp = fmaf(xs[jj], wf2[jj], fp);                                         \
      ip = fmaf(xs[jj], wi2[jj], ip);                                         \
      kp = fmaf(xs[jj], wk[jj], kp);                                          \
    }                                                                         \
    const float ls = logsig2(fp);                                             \
    cl[t] = ls;                                                               \
    const float ik = ex2(ip) * kp * 0.125f;                                   \
    ikv[t] = ik;                                                              \
    if (oh) { sIK[BUF][t][lc2] = ik; sLs[BUF][t][lc2] = ls; }                 \
  }                                                                           \
  _Pragma("unroll") for (int t = 1; t < 16; ++t) cl[t] += cl[t - 1];          \
  const float m = cl[7];                                                      \
  sEM[BUF][lane] = ex2(m);                                                    \
  sCF[BUF][lane] = ex2(cl[15] - m);                                           \
  unsigned short kvv[16];                                                     \
  _Pragma("unroll") for (int t = 0; t < 16; ++t) {                            \
    const float u = ikv[t] * ex2(m - cl[t]);                                  \
    kvv[t] = f2bf(u);                                                         \
    sKt[BUF][t][lane] = kvv[t];                                               \
  }                                                                           \
  _Pragma("unroll") for (int g = 0; g < 4; ++g) {                             \
    short4v pk = {(short)kvv[4 * g], (short)kvv[4 * g + 1],                   \
                  (short)kvv[4 * g + 2], (short)kvv[4 * g + 3]};              \
    *(short4v*)&sKnT[BUF][lane][4 * g] = pk;                                  \
  }                                                                           \
} while (0)

// ---- w3: q~ (own f for the per-t scale) + Sq (lanes<16) ----
#define PROD_Q(BUF, XP) do {                                                  \
  float qv[16], cl[16];                                                       \
  _Pragma("unroll") for (int t = 0; t < 16; ++t) {                            \
    float xs[7];                                                              \
    _Pragma("unroll") for (int jj = 0; jj < 7; ++jj) xs[jj] = (XP)[t * 7 + jj]; \
    float qq = bQ, fp = bF2;                                                  \
    _Pragma("unroll") for (int jj = 0; jj < 7; ++jj) {                        \
      qq = fmaf(xs[jj], wq[jj], qq);                                          \
      fp = fmaf(xs[jj], wf2[jj], fp);                                         \
    }                                                                         \
    qv[t] = qq;                                                               \
    cl[t] = logsig2(fp);                                                      \
  }                                                                           \
  _Pragma("unroll") for (int t = 1; t < 16; ++t) cl[t] += cl[t - 1];          \
  const float m = cl[7];                                                      \
  _Pragma("unroll") for (int t = 0; t < 16; ++t)                              \
    sQt[BUF][t][lane] = f2bf(qv[t] * ex2(cl[t] - m));                         \
  if (lane < 16) {                                                            \
    float Sqv = wqs[7];                                                       \
    _Pragma("unroll") for (int jj = 0; jj < 7; ++jj)                          \
      Sqv = fmaf((XP)[lane * 7 + jj], wqs[jj], Sqv);                          \
    sSq[BUF][lane] = Sqv;                                                     \
  }                                                                           \
} while (0)

// Row-split wave-specialized mLSTM: 1024 blocks x 256 threads (4 waves).
// Block bb: batch bb>>1, rows [32*(bb&1), +32). w0/w1 consumers (16 C-rows each,
// all 64 cols; + v for own rows); w2: i,k,f producer (64 ch); w3: q~ + Sq.
// Producers one chunk ahead (single barrier per chunk). 4 blocks/CU -> 4
// independent barrier domains per CU. LDS 40,704 B -> 40,960 alloc (4 x 40,960
// = 160 KiB exactly). sS stride 32, FULLY zeroed once: the K=32 A-fragment
// reads cols 16..31, which must be true zeros (bf16 junk can be NaN; NaN*0=NaN
// -- the R4 failure). ft reconstructed as em*cf (saves the sFtot array).
__global__ __launch_bounds__(256, 4) void mlstm_rs(
    const float* __restrict__ x,
    const float* __restrict__ Cin,
    const float* __restrict__ nin,
    const float* __restrict__ Wq, const float* __restrict__ bq,
    const float* __restrict__ Wk, const float* __restrict__ bk,
    const float* __restrict__ Wv, const float* __restrict__ bv,
    const float* __restrict__ Wi, const float* __restrict__ bi,
    const float* __restrict__ Wf, const float* __restrict__ bf,
    const float* __restrict__ Wo, const float* __restrict__ bo,
    float* __restrict__ hout, float* __restrict__ Cout, float* __restrict__ nout)
{
  const int bb   = blockIdx.x;
  const int b    = bb >> 1;
  const int half = bb & 1;
  const int rbase = half << 5;
  const int tid  = threadIdx.x;
  const int lane = tid & 63;
  const int w    = __builtin_amdgcn_readfirstlane(tid >> 6);  // wave 0..3
  const int quad = lane >> 4;
  const int sl   = lane & 15;

  __shared__ __align__(16) unsigned short sQt[2][L_][72];   // q~ [t][c] (c=64)
  __shared__ __align__(16) unsigned short sKt[2][L_][72];   // k~ [s][c]
  __shared__ __align__(16) unsigned short sKnT[2][H_][40];  // k~^T [c][s] (s16..31 = 0)
  __shared__ __align__(16) unsigned short sVT[2][32][40];   // v [r_local][s] (s16..31 = 0)
  __shared__ __align__(16) unsigned short sS[2][L_][32];    // masked S per consumer wave (16..31 = 0)
  __shared__ __align__(16) unsigned short sC0[32][72];      // C0*2^m [r_local][c]
  __shared__ float sLs[2][L_][32];   // log2(sigmoid(f)) own 32 channels
  __shared__ float sIK[2][L_][32];   // i*k (scaled) own 32 channels
  __shared__ float sSq[2][L_];       // sum_r q_t[r]
  __shared__ float sEM[2][H_];       // 2^{cl7}
  __shared__ float sCF[2][H_];       // 2^{cl15-cl7}
  __shared__ float sNv[32];

  // zero: sKnT pads (2x64 rows), sVT pads (2x32 rows), ALL of sS
  for (int idx = tid; idx < 1024; idx += 256) {
    const int r = idx >> 3, d = idx & 7;
    ((unsigned*)sKnT)[r * 20 + 8 + d] = 0;
  }
  for (int idx = tid; idx < 512; idx += 256) {
    const int r = idx >> 3, d = idx & 7;
    ((unsigned*)sVT)[r * 20 + 8 + d] = 0;
  }
  for (int idx = tid; idx < 512; idx += 256) ((unsigned*)sS)[idx] = 0;

  const float* __restrict__ xb = x + (size_t)b * T_ * I_;

  if (w < 2) {
    // ================== CONSUMERS ==================
    const int lc  = 16 * w + sl;      // block-local channel/row 0..31
    const int c0g = rbase + lc;       // global channel/row
    float wOl[7], wVl[7];
#pragma unroll
    for (int jj = 0; jj < 7; ++jj) {
      wOl[jj] = Wo[c0g * 7 + jj] * L2E;
      wVl[jj] = Wv[c0g * 7 + jj];
    }
    const float bO2 = bo[c0g] * L2E, bV = bv[c0g];
    f32x4 Cacc[4];
#pragma unroll
    for (int ct = 0; ct < 4; ++ct)
#pragma unroll
      for (int reg = 0; reg < 4; ++reg)
        Cacc[ct][reg] = Cin[(size_t)b * H_ * H_ +
                            (size_t)(rbase + 16 * w + 4 * quad + reg) * H_ + 16 * ct + sl];
    float nv = nin[(size_t)b * H_ * H_ + c0g];
    CONS_V(0, xb);
    __syncthreads();  // B0
    for (int j = 0; j < NCH_; ++j) {
      const int p = j & 1, pn = p ^ 1;
      const float* xc = xb + (size_t)j * L_ * I_;
      const float* xn = xc + L_ * I_;
      // ---- n-scan for own channel (serial chain; fs = 2^ls exactly) ----
      float den4[4];
#pragma unroll
      for (int t = 0; t < 16; ++t) {
        const float fs = ex2(sLs[p][t][lc]);
        nv = fmaf(fs, nv, sIK[p][t][lc]);
        if ((t >> 2) == quad) den4[t & 3] = nv;
      }
      // ---- S = Q~ K~^T ----
      const bf16x8 aQ0 = *(const bf16x8*)&sQt[p][sl][8 * quad];
      const bf16x8 aQ1 = *(const bf16x8*)&sQt[p][sl][32 + 8 * quad];
      const bf16x8 bK0 = *(const bf16x8*)&sKt[p][sl][8 * quad];
      const bf16x8 bK1 = *(const bf16x8*)&sKt[p][sl][32 + 8 * quad];
      f32x4 Sv = {0.f, 0.f, 0.f, 0.f};
      Sv = __builtin_amdgcn_mfma_f32_16x16x32_bf16(aQ0, bK0, Sv, 0, 0, 0);
      Sv = __builtin_amdgcn_mfma_f32_16x16x32_bf16(aQ1, bK1, Sv, 0, 0, 0);
      // ---- idn + o for own 4 t's ----
      float idn[4], oo[4];
#pragma unroll
      for (int r2 = 0; r2 < 4; ++r2) {
        const int t = 4 * quad + r2;
        idn[r2] = __fdividef(1.f, fmaxf(den4[r2] * sSq[p][t], 1.f));
        float op = bO2;
#pragma unroll
        for (int jj = 0; jj < 7; ++jj) op = fmaf(xc[t * 7 + jj], wOl[jj], op);
        oo[r2] = sig2(op);
      }
      // ---- masked S write (private buffer, cols 0..15 only; 16..31 stay 0) ----
#pragma unroll
      for (int reg = 0; reg < 4; ++reg) {
        const int t = 4 * quad + reg;
        sS[w][t][sl] = f2bf((sl <= t) ? Sv[reg] : 0.f);
      }
      // ---- C0 snapshot + G = V k~^T ----
      const bf16x8 aV = *(const bf16x8*)&sVT[p][16 * w + sl][8 * quad];
      f32x4 G[4];
      float ftA[4], cfA[4];
#pragma unroll
      for (int ct = 0; ct < 4; ++ct) {
        const int cc = 16 * ct + sl;
        const float emv = sEM[p][cc];
        cfA[ct] = sCF[p][cc];
        ftA[ct] = emv * cfA[ct];   // 2^{cl15}
#pragma unroll
        for (int reg = 0; reg < 4; ++reg)
          sC0[16 * w + 4 * quad + reg][cc] = f2bf(Cacc[ct][reg] * emv);
        const bf16x8 bKn = *(const bf16x8*)&sKnT[p][cc][8 * quad];
        f32x4 z = {0.f, 0.f, 0.f, 0.f};
        G[ct] = __builtin_amdgcn_mfma_f32_16x16x32_bf16(aV, bKn, z, 0, 0, 0);
      }
      // ---- v for next chunk (independent, fills MFMA latency) ----
      if (j + 1 < NCH_) CONS_V(pn, xn);
      // ---- Num = Q~ C0^T + (M.S) V^T ----
      const bf16x8 bC0a = *(const bf16x8*)&sC0[16 * w + sl][8 * quad];
      const bf16x8 bC0b = *(const bf16x8*)&sC0[16 * w + sl][32 + 8 * quad];
      const bf16x8 aS   = *(const bf16x8*)&sS[w][sl][8 * quad];
      f32x4 Num = {0.f, 0.f, 0.f, 0.f};
      Num = __builtin_amdgcn_mfma_f32_16x16x32_bf16(aQ0, bC0a, Num, 0, 0, 0);
      Num = __builtin_amdgcn_mfma_f32_16x16x32_bf16(aQ1, bC0b, Num, 0, 0, 0);
      Num = __builtin_amdgcn_mfma_f32_16x16x32_bf16(aS, aV, Num, 0, 0, 0);
      // ---- h ----
#pragma unroll
      for (int reg = 0; reg < 4; ++reg) {
        const int t = 4 * quad + reg;
        const float y = Num[reg] * idn[reg];
        const float e = ex2(y * 2.88539008178f);  // e^{2y}
        const float th = 1.f - __fdividef(2.f, e + 1.f);
        hout[(size_t)b * T_ * H_ + (size_t)(j * L_ + t) * H_ + c0g] = oo[reg] * th;
      }
      // ---- C update: ft*C + cf*G ----
#pragma unroll
      for (int ct = 0; ct < 4; ++ct) Cacc[ct] = Cacc[ct] * ftA[ct] + G[ct] * cfA[ct];
      __syncthreads();
    }
#pragma unroll
    for (int ct = 0; ct < 4; ++ct)
#pragma unroll
      for (int reg = 0; reg < 4; ++reg)
        Cout[(size_t)b * H_ * H_ +
             (size_t)(rbase + 16 * w + 4 * quad + reg) * H_ + 16 * ct + sl] = Cacc[ct][reg];
    if (quad == 0) sNv[lc] = nv;
  } else if (w == 2) {
    // ================== i,k,f producer ==================
    float wi2[7], wk[7], wf2[7];
#pragma unroll
    for (int jj = 0; jj < 7; ++jj) {
      wi2[jj] = Wi[lane * 7 + jj] * L2E;
      wk[jj]  = Wk[lane * 7 + jj];
      wf2[jj] = Wf[lane * 7 + jj] * L2E;
    }
    const float bI2 = bi[lane] * L2E, bK = bk[lane], bF2 = bf[lane] * L2E;
    const int oh  = ((lane >> 5) == half);
    const int lc2 = lane & 31;
    PROD_IKF(0, xb);
    __syncthreads();  // B0
    for (int j = 0; j < NCH_; ++j) {
      if (j + 1 < NCH_) {
        const int pn = (j + 1) & 1;
        const float* xn = xb + (size_t)(j + 1) * L_ * I_;
        PROD_IKF(pn, xn);
      }
      __syncthreads();
    }
  } else {
    // ================== q producer + Sq ==================
    float wq[7], wf2[7];
#pragma unroll
    for (int jj = 0; jj < 7; ++jj) {
      wq[jj]  = Wq[lane * 7 + jj];
      wf2[jj] = Wf[lane * 7 + jj] * L2E;
    }
    const float bQ = bq[lane], bF2 = bf[lane] * L2E;
    float wqs[8];
#pragma unroll
    for (int jj = 0; jj < 7; ++jj) {
      float s = wq[jj];
#pragma unroll
      for (int off = 32; off >= 1; off >>= 1) s += __shfl_xor(s, off);
      wqs[jj] = s;
    }
    {
      float s = bQ;
#pragma unroll
      for (int off = 32; off >= 1; off >>= 1) s += __shfl_xor(s, off);
      wqs[7] = s;
    }
    PROD_Q(0, xb);
    __syncthreads();  // B0
    for (int j = 0; j < NCH_; ++j) {
      if (j + 1 < NCH_) {
        const int pn = (j + 1) & 1;
        const float* xn = xb + (size_t)(j + 1) * L_ * I_;
        PROD_Q(pn, xn);
      }
      __syncthreads();
    }
  }

  __syncthreads();  // final: sNv ready
  // nout: all 64 rows x own 32 cols (n rows are identical)
#pragma unroll
  for (int k = 0; k < 8; ++k) {
    const int idx = tid * 8 + k;
    const int r = idx >> 5, cl2 = idx & 31;
    nout[(size_t)b * H_ * H_ + (size_t)r * H_ + rbase + cl2] = sNv[cl2];
  }
}

extern "C" void kernel_launch(void* const* d_in, const int* in_sizes, int n_in,
                              void* d_out, int out_size, void* d_ws, size_t ws_size,
                              hipStream_t stream) {
  const float* xp  = (const float*)d_in[0];
  const float* Cp  = (const float*)d_in[1];
  const float* np_ = (const float*)d_in[2];

  const float* W[6];
  const float* Bv[6];
  if (n_in >= 15 && in_sizes[4] == 64) {
    for (int g = 0; g < 6; ++g) {
      W[g]  = (const float*)d_in[3 + 2 * g];
      Bv[g] = (const float*)d_in[4 + 2 * g];
    }
  } else {
    for (int g = 0; g < 6; ++g) {
      W[g]  = (const float*)d_in[3 + g];
      Bv[g] = (const float*)d_in[9 + g];
    }
  }

  float* hout = (float*)d_out;
  float* Cout = hout + (size_t)B_ * T_ * H_;
  float* nout = Cout + (size_t)B_ * H_ * H_;

  mlstm_rs<<<dim3(B_ * 2), dim3(256), 0, stream>>>(
      xp, Cp, np_,
      W[0], Bv[0], W[1], Bv[1], W[2], Bv[2],
      W[3], Bv[3], W[4], Bv[4], W[5], Bv[5],
      hout, Cout, nout);
}

// Round 8
// 177.826 us; speedup vs baseline: 1.5991x; 1.5991x over previous
//
#include <hip/hip_runtime.h>
#include <math.h>

#define B_ 512
#define T_ 256
#define I_ 7
#define H_ 64
#define L_ 16
#define NCH_ (T_ / L_)
#define L2E 1.44269504089f
#define GUARD2 (-21.64f)

typedef short bf16x8 __attribute__((ext_vector_type(8)));
typedef short short4v __attribute__((ext_vector_type(4)));
typedef float f32x4 __attribute__((ext_vector_type(4)));

__device__ __forceinline__ unsigned short f2bf(float f) {
  unsigned u = __float_as_uint(f);
  u += 0x7fff + ((u >> 16) & 1);          // RNE
  return (unsigned short)(u >> 16);
}
__device__ __forceinline__ float bf2f(unsigned short u) {
  return __uint_as_float(((unsigned)u) << 16);
}
__device__ __forceinline__ float ex2(float x) { return __builtin_amdgcn_exp2f(x); }
__device__ __forceinline__ float lg2(float x) { return __builtin_amdgcn_logf(x); }
// log2(sigmoid(a)) given a already scaled by log2e
__device__ __forceinline__ float logsig2(float a2) {
  return (a2 < GUARD2) ? a2 : -lg2(1.f + ex2(-a2));
}
__device__ __forceinline__ float sig2(float a2) {
  return __fdividef(1.f, 1.f + ex2(-a2));
}

// ---------------- producer duty macros (no barriers inside) ----------------
// w4/w5 (t-half tb): PRE(c): x-projections for i,k; ik -> ik8 regs + sIK[c].
#define DO_PRE(C) do {                                                        \
  const float* xp_ = xb + (C) * (L_ * I_);                                    \
  _Pragma("unroll") for (int tt = 0; tt < 8; ++tt) {                          \
    const int t = tb + tt;                                                    \
    float xs[7];                                                              \
    _Pragma("unroll") for (int jj = 0; jj < 7; ++jj) xs[jj] = xp_[t * 7 + jj];\
    float ip = bI2, kp = bK;                                                  \
    _Pragma("unroll") for (int jj = 0; jj < 7; ++jj) {                        \
      ip = fmaf(xs[jj], wi2[jj], ip);                                         \
      kp = fmaf(xs[jj], wk[jj], kp);                                          \
    }                                                                         \
    const float ik = ex2(ip) * kp * 0.125f;                                   \
    ik8[tt] = ik;                                                             \
    sIK[(C) & 1][t][lane] = ik;                                               \
  }                                                                           \
} while (0)

// w4/w5: EXP(c): k~ = ik*2^{m-cl}, k^ = k~*2^{cl15-m} from sLs(c); + v-pack(c).
#define DO_EXPV(C) do {                                                       \
  const float* xp_ = xb + (C) * (L_ * I_);                                    \
  float lsv[16];                                                              \
  _Pragma("unroll") for (int t = 0; t < 16; ++t) lsv[t] = sLs[(C) & 1][lane][t]; \
  _Pragma("unroll") for (int t = 1; t < 16; ++t) lsv[t] += lsv[t - 1];        \
  const float m = lsv[7];                                                     \
  const float scl = ex2(lsv[15] - m);                                         \
  unsigned short kh[8], vv[8];                                                \
  _Pragma("unroll") for (int tt = 0; tt < 8; ++tt) {                          \
    const int t = tb + tt;                                                    \
    const float u = ik8[tt] * ex2(m - lsv[t]);                                \
    sKt[(C) & 1][t][lane] = f2bf(u);                                          \
    kh[tt] = f2bf(u * scl);                                                   \
    float vp = bV;                                                            \
    _Pragma("unroll") for (int jj = 0; jj < 7; ++jj)                          \
      vp = fmaf(xp_[t * 7 + jj], wv[jj], vp);                                 \
    vv[tt] = f2bf(vp);                                                        \
  }                                                                           \
  { short4v p0 = {(short)kh[0], (short)kh[1], (short)kh[2], (short)kh[3]};    \
    short4v p1 = {(short)kh[4], (short)kh[5], (short)kh[6], (short)kh[7]};    \
    *(short4v*)&sKnT[(C) & 1][lane][tb]     = p0;                             \
    *(short4v*)&sKnT[(C) & 1][lane][tb + 4] = p1;                             \
    short4v q0 = {(short)vv[0], (short)vv[1], (short)vv[2], (short)vv[3]};    \
    short4v q1 = {(short)vv[4], (short)vv[5], (short)vv[6], (short)vv[7]};    \
    *(short4v*)&sVT[(C) & 1][lane][tb]     = q0;                              \
    *(short4v*)&sVT[(C) & 1][lane][tb + 4] = q1; }                            \
} while (0)

// w6: F(c): per-t log2(sigmoid(f)) -> sLs; 2^{cl7}, 2^{cl15} scalars; Sq(c).
#define DO_F(C) do {                                                          \
  const float* xp_ = xb + (C) * (L_ * I_);                                    \
  float ls[16];                                                               \
  _Pragma("unroll") for (int t = 0; t < 16; ++t) {                            \
    float fp = bF2;                                                           \
    _Pragma("unroll") for (int jj = 0; jj < 7; ++jj)                          \
      fp = fmaf(xp_[t * 7 + jj], wf2[jj], fp);                                \
    ls[t] = logsig2(fp);                                                      \
    sLs[(C) & 1][lane][t] = ls[t];                                            \
  }                                                                           \
  _Pragma("unroll") for (int t = 1; t < 16; ++t) ls[t] += ls[t - 1];          \
  sEM[(C) % 3][lane]   = ex2(ls[7]);                                          \
  sFtot[(C) % 3][lane] = ex2(ls[15]);                                         \
  if (lane < 16) {                                                            \
    float Sqv = wqs[7];                                                       \
    _Pragma("unroll") for (int jj = 0; jj < 7; ++jj)                          \
      Sqv = fmaf(xp_[lane * 7 + jj], wqs[jj], Sqv);                           \
    sSq[(C) & 1][lane] = Sqv;                                                 \
  }                                                                           \
} while (0)

// w7: invden(c) (exact n-scan, fs = 2^ls), q~(c), o-preact(c).
#define DO_W7(C) do {                                                         \
  const float* xp_ = xb + (C) * (L_ * I_);                                    \
  float lsv[16];                                                              \
  _Pragma("unroll") for (int t = 0; t < 16; ++t) {                            \
    lsv[t] = sLs[(C) & 1][lane][t];                                           \
    const float fs = ex2(lsv[t]);                                             \
    nv = fmaf(fs, nv, sIK[(C) & 1][t][lane]);                                 \
    sInvDen[(C) & 1][t][lane] =                                               \
        __fdividef(1.f, fmaxf(nv * sSq[(C) & 1][t], 1.f));                    \
  }                                                                           \
  float qv[16];                                                               \
  _Pragma("unroll") for (int t = 0; t < 16; ++t) {                            \
    float qq = bQ, op = bO2;                                                  \
    _Pragma("unroll") for (int jj = 0; jj < 7; ++jj) {                        \
      qq = fmaf(xp_[t * 7 + jj], wq[jj], qq);                                 \
      op = fmaf(xp_[t * 7 + jj], wo2[jj], op);                                \
    }                                                                         \
    qv[t] = qq;                                                               \
    sOpre[(C) & 1][t][lane] = f2bf(op);                                       \
  }                                                                           \
  _Pragma("unroll") for (int t = 1; t < 16; ++t) lsv[t] += lsv[t - 1];        \
  const float m = lsv[7];                                                     \
  _Pragma("unroll") for (int t = 0; t < 16; ++t)                              \
    sQt[(C) & 1][t][lane] = f2bf(qv[t] * ex2(lsv[t] - m));                    \
} while (0)

// Depth-2 pipelined wave-specialized mLSTM, UNIFIED barrier structure:
// every __syncthreads() is at top-level code executed unconditionally by all
// 8 waves (HIP-spec compliant; the per-role-loop variant with textually
// divergent barriers is UB and is the prime suspect for the R6/R7 GPU hangs).
// Dataflow identical to mlstm_p2: region j = consumers(chunk j) ||
// w4/5: EXPV(j+1)+v, PRE(j+2) || w6: F(j+2)+Sq(j+2) || w7: invden/q/o(j+1).
// All buffers 2-buffered except sEM/sFtot (3-buffered, written@j for j+2).
// sS fully zeroed once (bf16 junk can be NaN; NaN*0=NaN through MFMA).
__global__ __launch_bounds__(512, 4) void mlstm_u(
    const float* __restrict__ x,
    const float* __restrict__ Cin,
    const float* __restrict__ nin,
    const float* __restrict__ Wq, const float* __restrict__ bq,
    const float* __restrict__ Wk, const float* __restrict__ bk,
    const float* __restrict__ Wv, const float* __restrict__ bv,
    const float* __restrict__ Wi, const float* __restrict__ bi,
    const float* __restrict__ Wf, const float* __restrict__ bf,
    const float* __restrict__ Wo, const float* __restrict__ bo,
    float* __restrict__ hout, float* __restrict__ Cout, float* __restrict__ nout)
{
  const int b    = blockIdx.x;
  const int tid  = threadIdx.x;
  const int lane = tid & 63;
  const int w    = __builtin_amdgcn_readfirstlane(tid >> 6);  // wave 0..7
  const int quad = lane >> 4;
  const int sl   = lane & 15;
  const int c0   = 16 * (w & 3) + sl;

  __shared__ __align__(16) unsigned short sQt[2][L_][72];   // q~ [t][c]
  __shared__ __align__(16) unsigned short sKt[2][L_][72];   // k~ [s][c]
  __shared__ __align__(16) unsigned short sKnT[2][H_][40];  // k^T [c][s] (s16..31 = 0)
  __shared__ __align__(16) unsigned short sVT[2][H_][40];   // v [r][s]   (s16..31 = 0)
  __shared__ __align__(16) unsigned short sS[4][L_][32];    // private masked S (16..31 = 0)
  __shared__ __align__(16) unsigned short sC0[H_][72];      // C0*2^m [r][c] (same-wave)
  __shared__ __align__(16) unsigned short sOpre[2][L_][72]; // o preact (base-2) [t][c]
  __shared__ float sInvDen[2][L_][68];  // 1/max(den,1) [t][c]
  __shared__ float sIK[2][L_][H_];      // i*k (scaled) [t][c]
  __shared__ float sLs[2][H_][17];      // log2(sigmoid(f)) [c][t]
  __shared__ float sSq[2][L_];          // sum_r q_t[r]
  __shared__ float sEM[3][H_];          // 2^{cl7}   (3-buf: chunk c -> c%3)
  __shared__ float sFtot[3][H_];        // 2^{cl15}
  __shared__ float sNv[H_];

  // zero pads: sKnT/sVT cols 16..31 (both buffers), ALL of sS
  for (int idx = tid; idx < 1024; idx += 512) {
    const int r = idx >> 3, d = idx & 7;
    ((unsigned*)sKnT)[r * 20 + 8 + d] = 0;
    ((unsigned*)sVT)[r * 20 + 8 + d]  = 0;
  }
  for (int idx = tid; idx < 1024; idx += 512) ((unsigned*)sS)[idx] = 0;

  const float* __restrict__ xb = x + (size_t)b * T_ * I_;

  // ---- role register state (only the owning wave's values are used) ----
  f32x4 Cacc[4];                                   // w0-3
  float wi2[7], wk[7], wv[7], ik8[8];              // w4/5
  float bI2 = 0.f, bK = 0.f, bV = 0.f;
  int tb = 0;
  float wf2[7], wqs[8];                            // w6
  float bF2 = 0.f;
  float wq[7], wo2[7];                             // w7
  float bQ = 0.f, bO2 = 0.f, nv = 0.f;

  if (w < 4) {
#pragma unroll
    for (int ct = 0; ct < 4; ++ct)
#pragma unroll
      for (int reg = 0; reg < 4; ++reg)
        Cacc[ct][reg] =
            Cin[(size_t)b * H_ * H_ + (size_t)(16 * w + 4 * quad + reg) * H_ + 16 * ct + sl];
  } else if (w < 6) {
    tb = (w == 4) ? 0 : 8;
#pragma unroll
    for (int jj = 0; jj < 7; ++jj) {
      wi2[jj] = Wi[lane * 7 + jj] * L2E;
      wk[jj]  = Wk[lane * 7 + jj];
      wv[jj]  = Wv[lane * 7 + jj];
    }
    bI2 = bi[lane] * L2E; bK = bk[lane]; bV = bv[lane];
  } else if (w == 6) {
#pragma unroll
    for (int jj = 0; jj < 7; ++jj) wf2[jj] = Wf[lane * 7 + jj] * L2E;
    bF2 = bf[lane] * L2E;
#pragma unroll
    for (int jj = 0; jj < 7; ++jj) {
      float s = Wq[lane * 7 + jj];
#pragma unroll
      for (int off = 32; off >= 1; off >>= 1) s += __shfl_xor(s, off);
      wqs[jj] = s;
    }
    {
      float s = bq[lane];
#pragma unroll
      for (int off = 32; off >= 1; off >>= 1) s += __shfl_xor(s, off);
      wqs[7] = s;
    }
  } else {
#pragma unroll
    for (int jj = 0; jj < 7; ++jj) {
      wq[jj]  = Wq[lane * 7 + jj];
      wo2[jj] = Wo[lane * 7 + jj] * L2E;
    }
    bQ = bq[lane]; bO2 = bo[lane] * L2E;
    nv = nin[(size_t)b * H_ * H_ + lane];
  }

  // ---- prologue region -2: PRE(0), F(0) ----
  if (w == 4 || w == 5) DO_PRE(0);
  else if (w == 6) DO_F(0);
  __syncthreads();  // uniform barrier #1

  // ---- prologue region -1: EXPV(0)+PRE(1), F(1), W7(0) ----
  if (w == 4 || w == 5) { DO_EXPV(0); DO_PRE(1); }
  else if (w == 6) DO_F(1);
  else if (w == 7) DO_W7(0);
  __syncthreads();  // uniform barrier #2

  // ---- main loop: one uniform barrier per chunk ----
#pragma unroll 1
  for (int j = 0; j < NCH_; ++j) {
    if (w < 4) {
      // ================== CONSUMER: chunk j ==================
      const int p  = j & 1;
      const int e3 = j % 3;
      const bf16x8 aQ0 = *(const bf16x8*)&sQt[p][sl][8 * quad];
      const bf16x8 aQ1 = *(const bf16x8*)&sQt[p][sl][32 + 8 * quad];
      const bf16x8 bK0 = *(const bf16x8*)&sKt[p][sl][8 * quad];
      const bf16x8 bK1 = *(const bf16x8*)&sKt[p][sl][32 + 8 * quad];
      f32x4 Sv = {0.f, 0.f, 0.f, 0.f};
      Sv = __builtin_amdgcn_mfma_f32_16x16x32_bf16(aQ0, bK0, Sv, 0, 0, 0);
      Sv = __builtin_amdgcn_mfma_f32_16x16x32_bf16(aQ1, bK1, Sv, 0, 0, 0);
#pragma unroll
      for (int reg = 0; reg < 4; ++reg) {
        const int t = 4 * quad + reg;
        sS[w][t][sl] = f2bf((sl <= t) ? Sv[reg] : 0.f);
      }
      const bf16x8 aV = *(const bf16x8*)&sVT[p][c0][8 * quad];
#pragma unroll
      for (int ct = 0; ct < 4; ++ct) {
        const int cc = 16 * ct + sl;
        const float em = sEM[e3][cc];
        const float ft = sFtot[e3][cc];
#pragma unroll
        for (int reg = 0; reg < 4; ++reg)
          sC0[16 * w + 4 * quad + reg][cc] = f2bf(Cacc[ct][reg] * em);
        Cacc[ct] *= ft;
        const bf16x8 bH = *(const bf16x8*)&sKnT[p][cc][8 * quad];
        Cacc[ct] = __builtin_amdgcn_mfma_f32_16x16x32_bf16(aV, bH, Cacc[ct], 0, 0, 0);
      }
      const bf16x8 bC0a = *(const bf16x8*)&sC0[c0][8 * quad];
      const bf16x8 bC0b = *(const bf16x8*)&sC0[c0][32 + 8 * quad];
      const bf16x8 aS   = *(const bf16x8*)&sS[w][sl][8 * quad];
      f32x4 Num = {0.f, 0.f, 0.f, 0.f};
      Num = __builtin_amdgcn_mfma_f32_16x16x32_bf16(aQ0, bC0a, Num, 0, 0, 0);
      Num = __builtin_amdgcn_mfma_f32_16x16x32_bf16(aQ1, bC0b, Num, 0, 0, 0);
      Num = __builtin_amdgcn_mfma_f32_16x16x32_bf16(aS, aV, Num, 0, 0, 0);
#pragma unroll
      for (int reg = 0; reg < 4; ++reg) {
        const int t = 4 * quad + reg;
        const float o   = sig2(bf2f(sOpre[p][t][c0]));
        const float idn = sInvDen[p][t][c0];
        const float y = Num[reg] * idn;
        const float e = ex2(y * 2.88539008178f);  // e^{2y}
        const float th = 1.f - __fdividef(2.f, e + 1.f);
        hout[(size_t)b * T_ * H_ + (size_t)(j * L_ + t) * H_ + c0] = o * th;
      }
    } else if (w < 6) {
      if (j + 1 < NCH_) DO_EXPV(j + 1);
      if (j + 2 < NCH_) DO_PRE(j + 2);
    } else if (w == 6) {
      if (j + 2 < NCH_) DO_F(j + 2);
    } else {
      if (j + 1 < NCH_) DO_W7(j + 1);
    }
    __syncthreads();  // uniform per-chunk barrier
  }

  // ---- epilogue ----
  if (w < 4) {
#pragma unroll
    for (int ct = 0; ct < 4; ++ct)
#pragma unroll
      for (int reg = 0; reg < 4; ++reg)
        Cout[(size_t)b * H_ * H_ + (size_t)(16 * w + 4 * quad + reg) * H_ + 16 * ct + sl] =
            Cacc[ct][reg];
  } else if (w == 7) {
    sNv[lane] = nv;
  }
  __syncthreads();  // uniform barrier: sNv ready
  {
    const float nvv = sNv[lane];
#pragma unroll
    for (int k = 0; k < 8; ++k)
      nout[(size_t)b * H_ * H_ + (size_t)(8 * w + k) * H_ + lane] = nvv;
  }
}

extern "C" void kernel_launch(void* const* d_in, const int* in_sizes, int n_in,
                              void* d_out, int out_size, void* d_ws, size_t ws_size,
                              hipStream_t stream) {
  const float* xp  = (const float*)d_in[0];
  const float* Cp  = (const float*)d_in[1];
  const float* np_ = (const float*)d_in[2];

  const float* W[6];
  const float* Bv[6];
  if (n_in >= 15 && in_sizes[4] == 64) {
    for (int g = 0; g < 6; ++g) {
      W[g]  = (const float*)d_in[3 + 2 * g];
      Bv[g] = (const float*)d_in[4 + 2 * g];
    }
  } else {
    for (int g = 0; g < 6; ++g) {
      W[g]  = (const float*)d_in[3 + g];
      Bv[g] = (const float*)d_in[9 + g];
    }
  }

  float* hout = (float*)d_out;
  float* Cout = hout + (size_t)B_ * T_ * H_;
  float* nout = Cout + (size_t)B_ * H_ * H_;

  mlstm_u<<<dim3(B_), dim3(512), 0, stream>>>(
      xp, Cp, np_,
      W[0], Bv[0], W[1], Bv[1], W[2], Bv[2],
      W[3], Bv[3], W[4], Bv[4], W[5], Bv[5],
      hout, Cout, nout);
}

// Round 9
// 145.557 us; speedup vs baseline: 1.9536x; 1.2217x over previous
//
#include <hip/hip_runtime.h>
#include <math.h>

#define B_ 512
#define T_ 256
#define I_ 7
#define H_ 64
#define L_ 16
#define NCH_ (T_ / L_)
#define L2E 1.44269504089f
#define GUARD2 (-21.64f)

typedef short bf16x8 __attribute__((ext_vector_type(8)));
typedef short short4v __attribute__((ext_vector_type(4)));
typedef float f32x4 __attribute__((ext_vector_type(4)));

__device__ __forceinline__ unsigned short f2bf(float f) {
  unsigned u = __float_as_uint(f);
  u += 0x7fff + ((u >> 16) & 1);          // RNE
  return (unsigned short)(u >> 16);
}
__device__ __forceinline__ float bf2f(unsigned short u) {
  return __uint_as_float(((unsigned)u) << 16);
}
__device__ __forceinline__ float ex2(float x) { return __builtin_amdgcn_exp2f(x); }
__device__ __forceinline__ float lg2(float x) { return __builtin_amdgcn_logf(x); }
// log2(sigmoid(a)) given a already scaled by log2e
__device__ __forceinline__ float logsig2(float a2) {
  return (a2 < GUARD2) ? a2 : -lg2(1.f + ex2(-a2));
}
__device__ __forceinline__ float sig2(float a2) {
  return __fdividef(1.f, 1.f + ex2(-a2));
}

// ---- consumer pack halves (chunk C, t-half th0): v for w0/w2, o for w1/w3 ----
#define PACK_V(C) do {                                                        \
  const float* xp_ = xb + (C) * (L_ * I_);                                    \
  unsigned short vv[8];                                                       \
  _Pragma("unroll") for (int tt = 0; tt < 8; ++tt) {                          \
    const int t = th0 + tt;                                                   \
    float vp = bP;                                                            \
    _Pragma("unroll") for (int jj = 0; jj < 7; ++jj)                          \
      vp = fmaf(xp_[t * 7 + jj], wP[jj], vp);                                 \
    vv[tt] = f2bf(vp);                                                        \
  }                                                                           \
  short4v p0 = {(short)vv[0], (short)vv[1], (short)vv[2], (short)vv[3]};      \
  short4v p1 = {(short)vv[4], (short)vv[5], (short)vv[6], (short)vv[7]};      \
  *(short4v*)&sVT[(C) & 1][lane][th0]     = p0;                               \
  *(short4v*)&sVT[(C) & 1][lane][th0 + 4] = p1;                               \
} while (0)

#define PACK_O(C) do {                                                        \
  const float* xp_ = xb + (C) * (L_ * I_);                                    \
  _Pragma("unroll") for (int tt = 0; tt < 8; ++tt) {                          \
    const int t = th0 + tt;                                                   \
    float op = bP;                                                            \
    _Pragma("unroll") for (int jj = 0; jj < 7; ++jj)                          \
      op = fmaf(xp_[t * 7 + jj], wP[jj], op);                                 \
    sOpre[(C) & 1][t][lane] = f2bf(op);                                       \
  }                                                                           \
} while (0)

// ---- w4/w5: i*k preacts + ik (t-half tb) ----
#define IK_PRE(C) do {                                                        \
  const float* xp_ = xb + (C) * (L_ * I_);                                    \
  _Pragma("unroll") for (int tt = 0; tt < 8; ++tt) {                          \
    const int t = tb + tt;                                                    \
    float xs[7];                                                              \
    _Pragma("unroll") for (int jj = 0; jj < 7; ++jj) xs[jj] = xp_[t * 7 + jj];\
    float ip = bI2, kp = bK;                                                  \
    _Pragma("unroll") for (int jj = 0; jj < 7; ++jj) {                        \
      ip = fmaf(xs[jj], wi2[jj], ip);                                         \
      kp = fmaf(xs[jj], wk[jj], kp);                                          \
    }                                                                         \
    const float ik = ex2(ip) * kp * 0.125f;                                   \
    ik8[tt] = ik;                                                             \
    sIK[(C) & 1][t][lane] = ik;                                               \
  }                                                                           \
} while (0)

// ---- w4/w5: k~ = ik*2^{m-cl}, k^ = ik*2^{cl15-cl} (prefix from sLs) ----
#define IK_EXP(C) do {                                                        \
  float cl[16];                                                               \
  _Pragma("unroll") for (int t = 0; t < 16; ++t) cl[t] = sLs[(C) & 1][lane][t]; \
  _Pragma("unroll") for (int t = 1; t < 16; ++t) cl[t] += cl[t - 1];          \
  const float m = cl[7];                                                      \
  const float scl = ex2(cl[15] - m);                                          \
  unsigned short kh[8];                                                       \
  _Pragma("unroll") for (int tt = 0; tt < 8; ++tt) {                          \
    const int t = tb + tt;                                                    \
    const float u = ik8[tt] * ex2(m - cl[t]);                                 \
    sKt[(C) & 1][t][lane] = f2bf(u);                                          \
    kh[tt] = f2bf(u * scl);                                                   \
  }                                                                           \
  short4v p0 = {(short)kh[0], (short)kh[1], (short)kh[2], (short)kh[3]};      \
  short4v p1 = {(short)kh[4], (short)kh[5], (short)kh[6], (short)kh[7]};      \
  *(short4v*)&sKnT[(C) & 1][lane][tb]     = p0;                               \
  *(short4v*)&sKnT[(C) & 1][lane][tb + 4] = p1;                               \
} while (0)

// ---- w6/w7: f-gate half (t = ftb..ftb+7) -> sLs ----
#define F_HALF(C) do {                                                        \
  const float* xp_ = xb + (C) * (L_ * I_);                                    \
  _Pragma("unroll") for (int tt = 0; tt < 8; ++tt) {                          \
    const int t = ftb + tt;                                                   \
    float fp = bF2;                                                           \
    _Pragma("unroll") for (int jj = 0; jj < 7; ++jj)                          \
      fp = fmaf(xp_[t * 7 + jj], wf2[jj], fp);                                \
    sLs[(C) & 1][lane][t] = logsig2(fp);                                      \
  }                                                                           \
} while (0)

// ---- w6: chunk scalars (2^{cl7}, 2^{cl15}) + Sq + q~ for t0-7 ----
#define SCALQ(C) do {                                                         \
  const float* xp_ = xb + (C) * (L_ * I_);                                    \
  float cl[16];                                                               \
  _Pragma("unroll") for (int t = 0; t < 16; ++t) cl[t] = sLs[(C) & 1][lane][t]; \
  _Pragma("unroll") for (int t = 1; t < 16; ++t) cl[t] += cl[t - 1];          \
  sEM[(C) & 1][lane]   = ex2(cl[7]);                                          \
  sFtot[(C) & 1][lane] = ex2(cl[15]);                                         \
  if (lane < 16) {                                                            \
    float Sqv = wqs[7];                                                       \
    _Pragma("unroll") for (int jj = 0; jj < 7; ++jj)                          \
      Sqv = fmaf(xp_[lane * 7 + jj], wqs[jj], Sqv);                           \
    sSq[(C) & 1][lane] = Sqv;                                                 \
  }                                                                           \
  const float m = cl[7];                                                      \
  _Pragma("unroll") for (int t = 0; t < 8; ++t) {                             \
    float qq = bQ;                                                            \
    _Pragma("unroll") for (int jj = 0; jj < 7; ++jj)                          \
      qq = fmaf(xp_[t * 7 + jj], wq[jj], qq);                                 \
    sQt[(C) & 1][t][lane] = f2bf(qq * ex2(cl[t] - m));                        \
  }                                                                           \
} while (0)

// ---- w7: den-scan (exact fp32, fs = 2^ls) + q~ for t8-15 ----
#define QDEN(C) do {                                                          \
  const float* xp_ = xb + (C) * (L_ * I_);                                    \
  float ls[16], cl[16];                                                       \
  _Pragma("unroll") for (int t = 0; t < 16; ++t) ls[t] = sLs[(C) & 1][lane][t]; \
  _Pragma("unroll") for (int t = 0; t < 16; ++t) {                            \
    nv = fmaf(ex2(ls[t]), nv, sIK[(C) & 1][t][lane]);                         \
    sDen[(C) & 1][t][lane] = nv;                                              \
  }                                                                           \
  cl[0] = ls[0];                                                              \
  _Pragma("unroll") for (int t = 1; t < 16; ++t) cl[t] = cl[t - 1] + ls[t];   \
  const float m = cl[7];                                                      \
  _Pragma("unroll") for (int t = 8; t < 16; ++t) {                            \
    float qq = bQ;                                                            \
    _Pragma("unroll") for (int jj = 0; jj < 7; ++jj)                          \
      qq = fmaf(xp_[t * 7 + jj], wq[jj], qq);                                 \
    sQt[(C) & 1][t][lane] = f2bf(qq * ex2(cl[t] - m));                        \
  }                                                                           \
} while (0)

// R2's proven per-role 2-barrier structure with poles flattened across 8 waves:
// region A(j): w0-3 P2(j) + {v|o}-pack-half(j+1); w4/5 IK_PRE(j+1); w6/7 F-half(j+1).
// region B(j): w0-3 P3(j)+h(j) (idn computed in-lane from sDen*sSq); w4/5 IK_EXP(j+1);
// w6 scalars+Sq+q~(t0-7)(j+1); w7 den-scan+q~(t8-15)(j+1).
// Every cross-wave LDS dep crosses >=1 barrier; all buffers 2-buffered (parity
// verified). sS fully zeroed once (bf16 junk can be NaN; NaN*0=NaN through MFMA).
// Per-role divergent barrier loops (R1/R2/R3/R5-proven shape; unified barriers
// spill the role-union register state -> 60 MB scratch traffic, R8).
__global__ __launch_bounds__(512, 4) void mlstm_bal(
    const float* __restrict__ x,
    const float* __restrict__ Cin,
    const float* __restrict__ nin,
    const float* __restrict__ Wq, const float* __restrict__ bq,
    const float* __restrict__ Wk, const float* __restrict__ bk,
    const float* __restrict__ Wv, const float* __restrict__ bv,
    const float* __restrict__ Wi, const float* __restrict__ bi,
    const float* __restrict__ Wf, const float* __restrict__ bf,
    const float* __restrict__ Wo, const float* __restrict__ bo,
    float* __restrict__ hout, float* __restrict__ Cout, float* __restrict__ nout)
{
  const int b    = blockIdx.x;
  const int tid  = threadIdx.x;
  const int lane = tid & 63;
  const int w    = __builtin_amdgcn_readfirstlane(tid >> 6);  // wave 0..7
  const int quad = lane >> 4;
  const int sl   = lane & 15;

  __shared__ __align__(16) unsigned short sQt[2][L_][72];   // q~ [t][c]
  __shared__ __align__(16) unsigned short sKt[2][L_][72];   // k~ [s][c]
  __shared__ __align__(16) unsigned short sKnT[2][H_][40];  // k^T [c][s] (s16..31 = 0)
  __shared__ __align__(16) unsigned short sVT[2][H_][40];   // v [r][s]   (s16..31 = 0)
  __shared__ __align__(16) unsigned short sS[4][L_][32];    // private masked S (16..31 = 0)
  __shared__ __align__(16) unsigned short sC0[H_][72];      // C0*2^m [r][c] (same-wave)
  __shared__ __align__(16) unsigned short sOpre[2][L_][72]; // o preact (base-2) [t][c]
  __shared__ float sDen[2][L_][68];  // n-scan value [t][c]
  __shared__ float sIK[2][L_][H_];   // i*k (scaled) [t][c]
  __shared__ float sLs[2][H_][17];   // log2(sigmoid(f)) [c][t]
  __shared__ float sSq[2][L_];       // sum_r q_t[r]
  __shared__ float sEM[2][H_];       // 2^{cl7}
  __shared__ float sFtot[2][H_];     // 2^{cl15}
  __shared__ float sNv[H_];

  // zero pads: sKnT/sVT cols 16..31 (both buffers), ALL of sS
  for (int idx = tid; idx < 1024; idx += 512) {
    const int r = idx >> 3, d = idx & 7;
    ((unsigned*)sKnT)[r * 20 + 8 + d] = 0;
    ((unsigned*)sVT)[r * 20 + 8 + d]  = 0;
  }
  for (int idx = tid; idx < 1024; idx += 512) ((unsigned*)sS)[idx] = 0;

  const float* __restrict__ xb = x + (size_t)b * T_ * I_;

  if (w < 4) {
    // ============ CONSUMERS + pack halves (w0/w2: v; w1/w3: o) ============
    const int c0  = 16 * w + sl;
    const int th0 = (w < 2) ? 0 : 8;   // w0,w1: t0-7; w2,w3: t8-15
    float wP[7];
    float bP;
    if ((w & 1) == 0) {
#pragma unroll
      for (int jj = 0; jj < 7; ++jj) wP[jj] = Wv[lane * 7 + jj];
      bP = bv[lane];
    } else {
#pragma unroll
      for (int jj = 0; jj < 7; ++jj) wP[jj] = Wo[lane * 7 + jj] * L2E;
      bP = bo[lane] * L2E;
    }
    f32x4 Cacc[4];
#pragma unroll
    for (int ct = 0; ct < 4; ++ct)
#pragma unroll
      for (int reg = 0; reg < 4; ++reg)
        Cacc[ct][reg] =
            Cin[(size_t)b * H_ * H_ + (size_t)(16 * w + 4 * quad + reg) * H_ + 16 * ct + sl];
    if ((w & 1) == 0) PACK_V(0); else PACK_O(0);
    __syncthreads();  // B0a
    __syncthreads();  // B0b
    for (int j = 0; j < NCH_; ++j) {
      const int p = j & 1;
      // ---- region A: P2 ----
      const bf16x8 aQ0 = *(const bf16x8*)&sQt[p][sl][8 * quad];
      const bf16x8 aQ1 = *(const bf16x8*)&sQt[p][sl][32 + 8 * quad];
      const bf16x8 bK0 = *(const bf16x8*)&sKt[p][sl][8 * quad];
      const bf16x8 bK1 = *(const bf16x8*)&sKt[p][sl][32 + 8 * quad];
      f32x4 Sv = {0.f, 0.f, 0.f, 0.f};
      Sv = __builtin_amdgcn_mfma_f32_16x16x32_bf16(aQ0, bK0, Sv, 0, 0, 0);
      Sv = __builtin_amdgcn_mfma_f32_16x16x32_bf16(aQ1, bK1, Sv, 0, 0, 0);
#pragma unroll
      for (int reg = 0; reg < 4; ++reg) {
        const int t = 4 * quad + reg;
        sS[w][t][sl] = f2bf((sl <= t) ? Sv[reg] : 0.f);
      }
      const bf16x8 aV = *(const bf16x8*)&sVT[p][c0][8 * quad];
#pragma unroll
      for (int ct = 0; ct < 4; ++ct) {
        const int cc = 16 * ct + sl;
        const float em = sEM[p][cc];
        const float ft = sFtot[p][cc];
#pragma unroll
        for (int reg = 0; reg < 4; ++reg)
          sC0[16 * w + 4 * quad + reg][cc] = f2bf(Cacc[ct][reg] * em);
        Cacc[ct] *= ft;
        const bf16x8 bH = *(const bf16x8*)&sKnT[p][cc][8 * quad];
        Cacc[ct] = __builtin_amdgcn_mfma_f32_16x16x32_bf16(aV, bH, Cacc[ct], 0, 0, 0);
      }
      if (j + 1 < NCH_) { if ((w & 1) == 0) PACK_V(j + 1); else PACK_O(j + 1); }
      __syncthreads();  // B1
      // ---- region B: P3 + h ----
      const bf16x8 bC0a = *(const bf16x8*)&sC0[c0][8 * quad];
      const bf16x8 bC0b = *(const bf16x8*)&sC0[c0][32 + 8 * quad];
      const bf16x8 aS   = *(const bf16x8*)&sS[w][sl][8 * quad];
      f32x4 Num = {0.f, 0.f, 0.f, 0.f};
      Num = __builtin_amdgcn_mfma_f32_16x16x32_bf16(aQ0, bC0a, Num, 0, 0, 0);
      Num = __builtin_amdgcn_mfma_f32_16x16x32_bf16(aQ1, bC0b, Num, 0, 0, 0);
      Num = __builtin_amdgcn_mfma_f32_16x16x32_bf16(aS, aV, Num, 0, 0, 0);
#pragma unroll
      for (int reg = 0; reg < 4; ++reg) {
        const int t = 4 * quad + reg;
        const float den = sDen[p][t][c0];
        const float idn = __fdividef(1.f, fmaxf(den * sSq[p][t], 1.f));
        const float o   = sig2(bf2f(sOpre[p][t][c0]));
        const float y = Num[reg] * idn;
        const float e = ex2(y * 2.88539008178f);  // e^{2y}
        const float th = 1.f - __fdividef(2.f, e + 1.f);
        hout[(size_t)b * T_ * H_ + (size_t)(j * L_ + t) * H_ + c0] = o * th;
      }
      __syncthreads();  // B2
    }
#pragma unroll
    for (int ct = 0; ct < 4; ++ct)
#pragma unroll
      for (int reg = 0; reg < 4; ++reg)
        Cout[(size_t)b * H_ * H_ + (size_t)(16 * w + 4 * quad + reg) * H_ + 16 * ct + sl] =
            Cacc[ct][reg];
  } else if (w == 4 || w == 5) {
    // ============ i*k producer (t-half tb) ============
    const int tb = (w == 4) ? 0 : 8;
    float wi2[7], wk[7];
#pragma unroll
    for (int jj = 0; jj < 7; ++jj) {
      wi2[jj] = Wi[lane * 7 + jj] * L2E;
      wk[jj]  = Wk[lane * 7 + jj];
    }
    const float bI2 = bi[lane] * L2E, bK = bk[lane];
    float ik8[8];
    IK_PRE(0);
    __syncthreads();  // B0a
    IK_EXP(0);
    __syncthreads();  // B0b
    for (int j = 0; j < NCH_; ++j) {
      if (j + 1 < NCH_) IK_PRE(j + 1);
      __syncthreads();  // B1
      if (j + 1 < NCH_) IK_EXP(j + 1);
      __syncthreads();  // B2
    }
  } else if (w == 6) {
    // ============ f-half (t0-7) + chunk scalars + Sq + q~(t0-7) ============
    const int ftb = 0;
    float wf2[7], wq[7], wqs[8];
#pragma unroll
    for (int jj = 0; jj < 7; ++jj) {
      wf2[jj] = Wf[lane * 7 + jj] * L2E;
      wq[jj]  = Wq[lane * 7 + jj];
    }
    const float bF2 = bf[lane] * L2E, bQ = bq[lane];
#pragma unroll
    for (int jj = 0; jj < 7; ++jj) {
      float s = wq[jj];
#pragma unroll
      for (int off = 32; off >= 1; off >>= 1) s += __shfl_xor(s, off);
      wqs[jj] = s;
    }
    {
      float s = bQ;
#pragma unroll
      for (int off = 32; off >= 1; off >>= 1) s += __shfl_xor(s, off);
      wqs[7] = s;
    }
    F_HALF(0);
    __syncthreads();  // B0a
    SCALQ(0);
    __syncthreads();  // B0b
    for (int j = 0; j < NCH_; ++j) {
      if (j + 1 < NCH_) F_HALF(j + 1);
      __syncthreads();  // B1
      if (j + 1 < NCH_) SCALQ(j + 1);
      __syncthreads();  // B2
    }
  } else {
    // ============ f-half (t8-15) + den-scan + q~(t8-15) ============
    const int ftb = 8;
    float wf2[7], wq[7];
#pragma unroll
    for (int jj = 0; jj < 7; ++jj) {
      wf2[jj] = Wf[lane * 7 + jj] * L2E;
      wq[jj]  = Wq[lane * 7 + jj];
    }
    const float bF2 = bf[lane] * L2E, bQ = bq[lane];
    float nv = nin[(size_t)b * H_ * H_ + lane];
    F_HALF(0);
    __syncthreads();  // B0a
    QDEN(0);
    __syncthreads();  // B0b
    for (int j = 0; j < NCH_; ++j) {
      if (j + 1 < NCH_) F_HALF(j + 1);
      __syncthreads();  // B1
      if (j + 1 < NCH_) QDEN(j + 1);
      __syncthreads();  // B2
    }
    sNv[lane] = nv;
  }

  __syncthreads();  // final: sNv ready
  {
    const float nvv = sNv[lane];
#pragma unroll
    for (int k = 0; k < 8; ++k)
      nout[(size_t)b * H_ * H_ + (size_t)(8 * w + k) * H_ + lane] = nvv;
  }
}

extern "C" void kernel_launch(void* const* d_in, const int* in_sizes, int n_in,
                              void* d_out, int out_size, void* d_ws, size_t ws_size,
                              hipStream_t stream) {
  const float* xp  = (const float*)d_in[0];
  const float* Cp  = (const float*)d_in[1];
  const float* np_ = (const float*)d_in[2];

  const float* W[6];
  const float* Bv[6];
  if (n_in >= 15 && in_sizes[4] == 64) {
    for (int g = 0; g < 6; ++g) {
      W[g]  = (const float*)d_in[3 + 2 * g];
      Bv[g] = (const float*)d_in[4 + 2 * g];
    }
  } else {
    for (int g = 0; g < 6; ++g) {
      W[g]  = (const float*)d_in[3 + g];
      Bv[g] = (const float*)d_in[9 + g];
    }
  }

  float* hout = (float*)d_out;
  float* Cout = hout + (size_t)B_ * T_ * H_;
  float* nout = Cout + (size_t)B_ * H_ * H_;

  mlstm_bal<<<dim3(B_), dim3(512), 0, stream>>>(
      xp, Cp, np_,
      W[0], Bv[0], W[1], Bv[1], W[2], Bv[2],
      W[3], Bv[3], W[4], Bv[4], W[5], Bv[5],
      hout, Cout, nout);
}